// Round 1
// baseline (914.957 us; speedup 1.0000x reference)
//
#include <hip/hip_runtime.h>

// LightGCN 3-layer propagation.
// out layout: [4, N_NODES, DIM] f32.
//   layer 0 = embeddings (copy)
//   layer l = SpMM(layer l-1):  y[dst] += w[e] * x[src]   (COO scatter-add)
//
// Round 1: correctness-first atomic scatter. 64 lanes per edge (1 lane/dim).
// Working set (25.6 MB/layer) is L2/L3-resident; bottleneck expected to be
// atomic-add throughput, to be profiled this round.

#define N_NODES 100000
#define DIM 64

__global__ void spmm_atomic_kernel(const float* __restrict__ x,      // [N_NODES, DIM] (prev layer)
                                   const float* __restrict__ ew,     // [E]
                                   const int* __restrict__ esrc,     // [E]
                                   const int* __restrict__ edst,     // [E]
                                   float* __restrict__ y,            // [N_NODES, DIM] (next layer, pre-zeroed)
                                   int n_edges) {
    long long tid = (long long)blockIdx.x * blockDim.x + threadIdx.x;
    int e = (int)(tid >> 6);   // edge index; 64 consecutive lanes share one edge
    int d = (int)(tid & 63);   // embedding dim
    if (e >= n_edges) return;
    // These three loads are wave-uniform (same e for all 64 lanes) -> L1/L2 broadcast.
    int s = esrc[e];
    int t = edst[e];
    float w = ew[e];
    float val = w * x[(long long)s * DIM + d];
    atomicAdd(&y[(long long)t * DIM + d], val);
}

extern "C" void kernel_launch(void* const* d_in, const int* in_sizes, int n_in,
                              void* d_out, int out_size, void* d_ws, size_t ws_size,
                              hipStream_t stream) {
    const float* emb  = (const float*)d_in[0];   // [N_NODES*DIM]
    const float* ew   = (const float*)d_in[1];   // [E]
    const int*   esrc = (const int*)d_in[2];     // [E]
    const int*   edst = (const int*)d_in[3];     // [E]
    float* out = (float*)d_out;                  // [4, N_NODES, DIM]

    const int n_edges = in_sizes[1];
    const size_t layer_elems = (size_t)N_NODES * DIM;

    // Layer 0: straight copy of embeddings.
    hipMemcpyAsync(out, emb, layer_elems * sizeof(float),
                   hipMemcpyDeviceToDevice, stream);

    // Zero layers 1..3 (d_out is poisoned to 0xAA before every launch).
    hipMemsetAsync(out + layer_elems, 0, 3 * layer_elems * sizeof(float), stream);

    // 64 threads per edge, 256-thread blocks -> 4 edges per block.
    const long long total_threads = (long long)n_edges * 64;
    const int blocks = (int)((total_threads + 255) / 256);

    for (int l = 1; l <= 3; ++l) {
        spmm_atomic_kernel<<<blocks, 256, 0, stream>>>(
            out + (size_t)(l - 1) * layer_elems, ew, esrc, edst,
            out + (size_t)l * layer_elems, n_edges);
    }
}

// Round 2
// 597.514 us; speedup vs baseline: 1.5313x; 1.5313x over previous
//
#include <hip/hip_runtime.h>

// LightGCN 3-layer propagation, CSR-per-launch version.
// out layout: [4, N_NODES, DIM] f32.
//   layer 0 = embeddings (copy)
//   layer l = SpMM(layer l-1):  y[d] = sum_{e: dst(e)=d} w[e] * x[src(e)]
//
// R1 showed the atomic scatter writes through: WRITE_SIZE = E*DIM*4 B = 300 MB
// per layer (12x the 25.6 MB ideal). R2 builds a dst-grouped CSR in d_ws once
// per launch (histogram -> scan -> scatter of {src,weight} pairs), then each
// layer is a pure gather with register accumulation: zero atomics in the hot
// loops, one coalesced 256 B store per node.

#define N_NODES 100000
#define DIM 64
#define SCAN_CHUNK 1024   // elements scanned per block in scan1 (256 thr x 4)

// ---------------- CSR build ----------------

__global__ void hist_kernel(const int* __restrict__ edst, int* __restrict__ deg, int E) {
    int e = blockIdx.x * blockDim.x + threadIdx.x;
    if (e < E) atomicAdd(&deg[edst[e]], 1);
}

// Per-block exclusive scan over chunks of 1024; emits per-block totals.
__global__ void scan1_kernel(const int* __restrict__ deg, int* __restrict__ off,
                             int* __restrict__ bsum, int n) {
    __shared__ int sdata[256];
    int tid = threadIdx.x;
    int base = blockIdx.x * SCAN_CHUNK + tid * 4;
    int v[4];
    #pragma unroll
    for (int i = 0; i < 4; ++i) v[i] = (base + i < n) ? deg[base + i] : 0;
    int tsum = v[0] + v[1] + v[2] + v[3];
    sdata[tid] = tsum;
    __syncthreads();
    // Hillis-Steele inclusive scan of 256 thread sums.
    for (int d = 1; d < 256; d <<= 1) {
        int t = (tid >= d) ? sdata[tid - d] : 0;
        __syncthreads();
        sdata[tid] += t;
        __syncthreads();
    }
    int excl = sdata[tid] - tsum;   // exclusive prefix of this thread's 4 elems
    if (tid == 255) bsum[blockIdx.x] = sdata[255];
    int run = excl;
    #pragma unroll
    for (int i = 0; i < 4; ++i) {
        if (base + i < n) off[base + i] = run;
        run += v[i];
    }
}

__global__ void scan2_kernel(int* __restrict__ bsum, int nb) {
    if (threadIdx.x == 0 && blockIdx.x == 0) {
        int a = 0;
        for (int i = 0; i < nb; ++i) { int t = bsum[i]; bsum[i] = a; a += t; }
    }
}

__global__ void scan3_kernel(int* __restrict__ off, const int* __restrict__ bsum, int n) {
    int i = blockIdx.x * blockDim.x + threadIdx.x;
    if (i < n) off[i] += bsum[i / SCAN_CHUNK];
}

// Scatter each edge's {src, weight} into its dst bucket (order within a bucket
// is race-determined; sum order only perturbs f32 rounding, well under thresh).
__global__ void scatter_kernel(const int* __restrict__ esrc, const int* __restrict__ edst,
                               const float* __restrict__ ew, const int* __restrict__ off,
                               int* __restrict__ cur, int2* __restrict__ pairs, int E) {
    int e = blockIdx.x * blockDim.x + threadIdx.x;
    if (e >= E) return;
    int d = edst[e];
    int p = off[d] + atomicAdd(&cur[d], 1);
    int2 pr;
    pr.x = esrc[e];
    pr.y = __float_as_int(ew[e]);
    pairs[p] = pr;
}

// ---------------- SpMM: one wave per node, lane = dim ----------------

__global__ void spmm_csr_kernel(const float* __restrict__ x,
                                const int2* __restrict__ pairs,
                                const int* __restrict__ off,
                                const int* __restrict__ deg,
                                float* __restrict__ y) {
    int gtid = blockIdx.x * blockDim.x + threadIdx.x;
    int node = gtid >> 6;
    int lane = threadIdx.x & 63;
    if (node >= N_NODES) return;
    int s0 = off[node];
    int n  = deg[node];
    float acc = 0.f;
    for (int k = 0; k < n; ++k) {
        int2 pr = pairs[s0 + k];                       // wave-uniform 8B load
        acc += __int_as_float(pr.y) * x[(size_t)pr.x * DIM + lane];  // coalesced 256B gather
    }
    y[(size_t)node * DIM + lane] = acc;
}

// ---------------- fallback (R1 atomic path, if ws too small) ----------------

__global__ void spmm_atomic_kernel(const float* __restrict__ x, const float* __restrict__ ew,
                                   const int* __restrict__ esrc, const int* __restrict__ edst,
                                   float* __restrict__ y, int n_edges) {
    long long tid = (long long)blockIdx.x * blockDim.x + threadIdx.x;
    int e = (int)(tid >> 6);
    int d = (int)(tid & 63);
    if (e >= n_edges) return;
    int s = esrc[e]; int t = edst[e]; float w = ew[e];
    atomicAdd(&y[(long long)t * DIM + d], w * x[(long long)s * DIM + d]);
}

extern "C" void kernel_launch(void* const* d_in, const int* in_sizes, int n_in,
                              void* d_out, int out_size, void* d_ws, size_t ws_size,
                              hipStream_t stream) {
    const float* emb  = (const float*)d_in[0];
    const float* ew   = (const float*)d_in[1];
    const int*   esrc = (const int*)d_in[2];
    const int*   edst = (const int*)d_in[3];
    float* out = (float*)d_out;

    const int E = in_sizes[1];
    const size_t layer_elems = (size_t)N_NODES * DIM;

    // Workspace layout (pairs first for 8B alignment).
    size_t need = (size_t)E * 8 + (size_t)3 * N_NODES * 4 + 512;
    // Layer 0: copy embeddings.
    hipMemcpyAsync(out, emb, layer_elems * sizeof(float), hipMemcpyDeviceToDevice, stream);

    if (ws_size >= need) {
        char* w = (char*)d_ws;
        int2* pairs = (int2*)w;
        int* deg  = (int*)(w + (size_t)E * 8);
        int* cur  = deg + N_NODES;
        int* off  = cur + N_NODES;
        int* bsum = off + N_NODES;

        // Zero deg+cur (ws is poisoned to 0xAA before every launch).
        hipMemsetAsync(deg, 0, (size_t)2 * N_NODES * 4, stream);

        const int eb = (E + 255) / 256;
        hist_kernel<<<eb, 256, 0, stream>>>(edst, deg, E);

        const int nscan = (N_NODES + SCAN_CHUNK - 1) / SCAN_CHUNK;   // 98
        scan1_kernel<<<nscan, 256, 0, stream>>>(deg, off, bsum, N_NODES);
        scan2_kernel<<<1, 64, 0, stream>>>(bsum, nscan);
        scan3_kernel<<<(N_NODES + 255) / 256, 256, 0, stream>>>(off, bsum, N_NODES);

        scatter_kernel<<<eb, 256, 0, stream>>>(esrc, edst, ew, off, cur, pairs, E);

        // 4 waves (nodes) per 256-thread block.
        const int nb = (N_NODES + 3) / 4;
        for (int l = 1; l <= 3; ++l) {
            spmm_csr_kernel<<<nb, 256, 0, stream>>>(
                out + (size_t)(l - 1) * layer_elems, pairs, off, deg,
                out + (size_t)l * layer_elems);
        }
    } else {
        // Fallback: R1 atomic scatter.
        hipMemsetAsync(out + layer_elems, 0, 3 * layer_elems * sizeof(float), stream);
        const long long total_threads = (long long)E * 64;
        const int blocks = (int)((total_threads + 255) / 256);
        for (int l = 1; l <= 3; ++l) {
            spmm_atomic_kernel<<<blocks, 256, 0, stream>>>(
                out + (size_t)(l - 1) * layer_elems, ew, esrc, edst,
                out + (size_t)l * layer_elems, E);
        }
    }
}

// Round 3
// 398.594 us; speedup vs baseline: 2.2955x; 1.4991x over previous
//
#include <hip/hip_runtime.h>

// LightGCN 3-layer propagation, CSR + quarter-wave gather version.
// out layout: [4, N_NODES, DIM] f32.
//   layer 0 = embeddings (copy)
//   layer l = SpMM(layer l-1):  y[d] = sum_{e: dst(e)=d} w[e] * x[src(e)]
//
// R2 counters: spmm WRITE ideal (25 MB) but latency-bound (VALUBusy 15%,
// 1.4 TB/s): one dependent pair->gather chain in flight, 12 trips/wave.
// R3: 4-edge-per-wave quarter scheme (16 lanes x float4 per edge row, trips/4,
// 4 independent gather chains in flight) + shfl_xor cross-quarter reduction.
// Also: scan2 serial loop -> 128-thread LDS scan.

#define N_NODES 100000
#define DIM 64
#define SCAN_CHUNK 1024   // elements scanned per block in scan1 (256 thr x 4)

// ---------------- CSR build ----------------

__global__ void hist_kernel(const int* __restrict__ edst, int* __restrict__ deg, int E) {
    int e = blockIdx.x * blockDim.x + threadIdx.x;
    if (e < E) atomicAdd(&deg[edst[e]], 1);
}

// Per-block exclusive scan over chunks of 1024; emits per-block totals.
__global__ void scan1_kernel(const int* __restrict__ deg, int* __restrict__ off,
                             int* __restrict__ bsum, int n) {
    __shared__ int sdata[256];
    int tid = threadIdx.x;
    int base = blockIdx.x * SCAN_CHUNK + tid * 4;
    int v[4];
    #pragma unroll
    for (int i = 0; i < 4; ++i) v[i] = (base + i < n) ? deg[base + i] : 0;
    int tsum = v[0] + v[1] + v[2] + v[3];
    sdata[tid] = tsum;
    __syncthreads();
    for (int d = 1; d < 256; d <<= 1) {
        int t = (tid >= d) ? sdata[tid - d] : 0;
        __syncthreads();
        sdata[tid] += t;
        __syncthreads();
    }
    int excl = sdata[tid] - tsum;
    if (tid == 255) bsum[blockIdx.x] = sdata[255];
    int run = excl;
    #pragma unroll
    for (int i = 0; i < 4; ++i) {
        if (base + i < n) off[base + i] = run;
        run += v[i];
    }
}

// Single-block 128-thread exclusive scan of the block sums (nb <= 128).
__global__ void scan2_kernel(int* __restrict__ bsum, int nb) {
    __shared__ int s[128];
    int tid = threadIdx.x;
    int v = (tid < nb) ? bsum[tid] : 0;
    s[tid] = v;
    __syncthreads();
    for (int d = 1; d < 128; d <<= 1) {
        int t = (tid >= d) ? s[tid - d] : 0;
        __syncthreads();
        s[tid] += t;
        __syncthreads();
    }
    if (tid < nb) bsum[tid] = s[tid] - v;   // exclusive
}

__global__ void scan3_kernel(int* __restrict__ off, const int* __restrict__ bsum, int n) {
    int i = blockIdx.x * blockDim.x + threadIdx.x;
    if (i < n) off[i] += bsum[i / SCAN_CHUNK];
}

// Scatter each edge's {src, weight} into its dst bucket.
__global__ void scatter_kernel(const int* __restrict__ esrc, const int* __restrict__ edst,
                               const float* __restrict__ ew, const int* __restrict__ off,
                               int* __restrict__ cur, int2* __restrict__ pairs, int E) {
    int e = blockIdx.x * blockDim.x + threadIdx.x;
    if (e >= E) return;
    int d = edst[e];
    int p = off[d] + atomicAdd(&cur[d], 1);
    int2 pr;
    pr.x = esrc[e];
    pr.y = __float_as_int(ew[e]);
    pairs[p] = pr;
}

// ---------------- SpMM: one wave per node, 4 edges in flight ----------------
// Quarter q (lanes 16q..16q+15) processes edges k = q, q+4, q+8, ...
// Each lane loads float4 -> a quarter covers the full 64-dim row (256 B).
// Cross-quarter sum via shfl_xor(16), shfl_xor(32); quarter 0 stores.

__global__ void spmm_csr_kernel(const float* __restrict__ x,
                                const int2* __restrict__ pairs,
                                const int* __restrict__ off,
                                const int* __restrict__ deg,
                                float* __restrict__ y) {
    int gtid = blockIdx.x * blockDim.x + threadIdx.x;
    int node = gtid >> 6;
    int lane = threadIdx.x & 63;
    int q  = lane >> 4;    // quarter 0..3 = which edge in the group of 4
    int ql = lane & 15;    // lane within quarter = which float4 of the row
    if (node >= N_NODES) return;
    int s0 = off[node];
    int n  = deg[node];
    float4 acc = make_float4(0.f, 0.f, 0.f, 0.f);
    for (int k = q; k < n; k += 4) {
        int2 pr = pairs[s0 + k];                 // uniform within quarter (32 B/wave)
        float w = __int_as_float(pr.y);
        const float4* row = (const float4*)(x + (size_t)pr.x * DIM);
        float4 v = row[ql];                      // 16 lanes x 16 B = 256 B coalesced
        acc.x += w * v.x;
        acc.y += w * v.y;
        acc.z += w * v.z;
        acc.w += w * v.w;
    }
    // Reduce the 4 quarters (same ql holds same dims).
    acc.x += __shfl_xor(acc.x, 16); acc.y += __shfl_xor(acc.y, 16);
    acc.z += __shfl_xor(acc.z, 16); acc.w += __shfl_xor(acc.w, 16);
    acc.x += __shfl_xor(acc.x, 32); acc.y += __shfl_xor(acc.y, 32);
    acc.z += __shfl_xor(acc.z, 32); acc.w += __shfl_xor(acc.w, 32);
    if (q == 0) {
        float4* yrow = (float4*)(y + (size_t)node * DIM);
        yrow[ql] = acc;                          // 16 lanes x 16 B = 256 B store
    }
}

// ---------------- fallback (atomic path, if ws too small) ----------------

__global__ void spmm_atomic_kernel(const float* __restrict__ x, const float* __restrict__ ew,
                                   const int* __restrict__ esrc, const int* __restrict__ edst,
                                   float* __restrict__ y, int n_edges) {
    long long tid = (long long)blockIdx.x * blockDim.x + threadIdx.x;
    int e = (int)(tid >> 6);
    int d = (int)(tid & 63);
    if (e >= n_edges) return;
    int s = esrc[e]; int t = edst[e]; float w = ew[e];
    atomicAdd(&y[(long long)t * DIM + d], w * x[(long long)s * DIM + d]);
}

extern "C" void kernel_launch(void* const* d_in, const int* in_sizes, int n_in,
                              void* d_out, int out_size, void* d_ws, size_t ws_size,
                              hipStream_t stream) {
    const float* emb  = (const float*)d_in[0];
    const float* ew   = (const float*)d_in[1];
    const int*   esrc = (const int*)d_in[2];
    const int*   edst = (const int*)d_in[3];
    float* out = (float*)d_out;

    const int E = in_sizes[1];
    const size_t layer_elems = (size_t)N_NODES * DIM;

    size_t need = (size_t)E * 8 + (size_t)3 * N_NODES * 4 + 512;
    hipMemcpyAsync(out, emb, layer_elems * sizeof(float), hipMemcpyDeviceToDevice, stream);

    if (ws_size >= need) {
        char* w = (char*)d_ws;
        int2* pairs = (int2*)w;
        int* deg  = (int*)(w + (size_t)E * 8);
        int* cur  = deg + N_NODES;
        int* off  = cur + N_NODES;
        int* bsum = off + N_NODES;

        hipMemsetAsync(deg, 0, (size_t)2 * N_NODES * 4, stream);

        const int eb = (E + 255) / 256;
        hist_kernel<<<eb, 256, 0, stream>>>(edst, deg, E);

        const int nscan = (N_NODES + SCAN_CHUNK - 1) / SCAN_CHUNK;   // 98
        scan1_kernel<<<nscan, 256, 0, stream>>>(deg, off, bsum, N_NODES);
        scan2_kernel<<<1, 128, 0, stream>>>(bsum, nscan);
        scan3_kernel<<<(N_NODES + 255) / 256, 256, 0, stream>>>(off, bsum, N_NODES);

        scatter_kernel<<<eb, 256, 0, stream>>>(esrc, edst, ew, off, cur, pairs, E);

        const int nb = (N_NODES + 3) / 4;   // 4 waves (nodes) per 256-thread block
        for (int l = 1; l <= 3; ++l) {
            spmm_csr_kernel<<<nb, 256, 0, stream>>>(
                out + (size_t)(l - 1) * layer_elems, pairs, off, deg,
                out + (size_t)l * layer_elems);
        }
    } else {
        hipMemsetAsync(out + layer_elems, 0, 3 * layer_elems * sizeof(float), stream);
        const long long total_threads = (long long)E * 64;
        const int blocks = (int)((total_threads + 255) / 256);
        for (int l = 1; l <= 3; ++l) {
            spmm_atomic_kernel<<<blocks, 256, 0, stream>>>(
                out + (size_t)(l - 1) * layer_elems, ew, esrc, edst,
                out + (size_t)l * layer_elems, E);
        }
    }
}